// Round 8
// baseline (96.097 us; speedup 1.0000x reference)
//
#include <hip/hip_runtime.h>

// SuperPointMatchesGenerator: B=8, N0=N1=2048 mutual-NN under homography.
// d_out f32, concat: gt_matches0[8,2048] | gt_matches1[8,2048] | min_dist0[8,2048]
//
// R8 vs R7 (90.0us): R7's dedup was right but its device atomicMin colkeys
// (2.1M u64 atomics, 128-way contention/address, cross-XCD serialization)
// cost more than the dedup saved. R8 keeps single-pass d2 but:
//  - column argmin via NON-ATOMIC per-(block,candidate) u64 partials
//    (owned by exactly one thread -> plain coalesced store, 16MB scratch)
//    + a 64-block reduce kernel (coalesced 128-way min per column).
//  - prep folded into main: candidates staged into a 32KB LDS slab (computing
//    b2 on the fly); the 16 row reprojections computed by lanes 0..15 once and
//    LDS-broadcast (was: every thread redundantly).
//  - rx2=2*rx trick kept (exact doubling distributes over rounding -> d2
//    bit-identical to reference (a2+b2)-2*ab).
//
// FP exactness vs numpy-f32 (no FMA contraction, explicit __f*_rn):
//   p_i = (H[i0]*x + H[i1]*y) + H[i2];  X = p0/(p2+1e-8);  a2 = X*X + Y*Y;
//   d2  = (a2 + b2) - 2*ab;  compare max(d2,0); winner e = sqrt(max(d2,0)).
// Keep-first argmin at every level: ascending c (thread-stride) / ascending r,
// strict <, u64 (d2bits<<32 | index) min => smallest index wins ties.
//
// ws (full path ~16.2MB): part u64[1024*2048] | colkeys u64[16384] | gt0p u16[16384]
// Fallback (ws too small): R6-proven dual-mode brute force in 64KB.

#define SPN 2048
#define SPT 16384
#define RPB 16            // rows per block (main)
#define BPB 128           // blocks per batch = SPN/RPB

__device__ __forceinline__ void sp_reproject(const float* __restrict__ T, int b,
                                             float x, float y,
                                             float& X, float& Y, float& S) {
  const float* H = T + b * 9;
  float p0 = __fadd_rn(__fadd_rn(__fmul_rn(H[0], x), __fmul_rn(H[1], y)), H[2]);
  float p1 = __fadd_rn(__fadd_rn(__fmul_rn(H[3], x), __fmul_rn(H[4], y)), H[5]);
  float p2 = __fadd_rn(__fadd_rn(__fmul_rn(H[6], x), __fmul_rn(H[7], y)), H[8]);
  float den = __fadd_rn(p2, 1e-8f);
  X = __fdiv_rn(p0, den);
  Y = __fdiv_rn(p1, den);
  S = __fadd_rn(__fmul_rn(X, X), __fmul_rn(Y, Y));
}

// 1024 blocks: block g = b*128+blk owns rows [blk*16, blk*16+16) of batch b.
// Row argmin -> gt0p + min_dist. Col partial (min over the 16 rows) -> part[g][c].
__global__ __launch_bounds__(256) void SuperPointMatchesGenerator_56925496541369_kernel(
    const float2* __restrict__ k0, const float2* __restrict__ k1,
    const float* __restrict__ T, unsigned short* __restrict__ gt0p,
    unsigned long long* __restrict__ part_out, float* __restrict__ out_mind) {
  __shared__ float4 cand[SPN];           // 32KB candidate slab (x, y, b2, pad)
  __shared__ float4 rowdat[RPB];         // (rx2, ry2, a2, pad)
  __shared__ unsigned long long red[4][RPB];

  const int g = blockIdx.x;
  const int b = g >> 7;                  // batch
  const int base_ib = (g & (BPB - 1)) * RPB;
  const int cb = b << 11;
  const int base = cb + base_ib;

  // stage candidates (coalesced float2 load, compute b2, LDS write)
  for (int u = threadIdx.x; u < SPN; u += 256) {
    float2 p = k1[cb + u];
    float s = __fadd_rn(__fmul_rn(p.x, p.x), __fmul_rn(p.y, p.y));
    cand[u] = make_float4(p.x, p.y, s, 0.0f);
  }
  // rows: lanes 0..15 reproject, broadcast via LDS
  if (threadIdx.x < RPB) {
    float2 p = k0[base + threadIdx.x];
    float X, Y, S;
    sp_reproject(T, b, p.x, p.y, X, Y, S);
    rowdat[threadIdx.x] = make_float4(__fadd_rn(X, X), __fadd_rn(Y, Y), S, 0.0f);
  }
  __syncthreads();

  float rx2[RPB], ry2[RPB], rs[RPB], bv[RPB];
  int bi[RPB];
#pragma unroll
  for (int r = 0; r < RPB; r++) {
    float4 v = rowdat[r];                // broadcast reads (no conflicts)
    rx2[r] = v.x; ry2[r] = v.y; rs[r] = v.z;
    bv[r] = INFINITY; bi[r] = 0;
  }

  unsigned long long* __restrict__ mypart = part_out + (size_t)g * SPN;
#pragma unroll 2
  for (int c = threadIdx.x; c < SPN; c += 256) {
    float4 v = cand[c];                  // ds_read_b128
    float cbv = INFINITY;
    int cbr = 0;
#pragma unroll
    for (int r = 0; r < RPB; r++) {
      float ab2 = __fadd_rn(__fmul_rn(rx2[r], v.x), __fmul_rn(ry2[r], v.y));
      float d2 = __fsub_rn(__fadd_rn(rs[r], v.z), ab2);
      float dm = fmaxf(d2, 0.0f);
      if (dm < bv[r]) { bv[r] = dm; bi[r] = c; }   // row argmin, keep-first in c
      if (dm < cbv)   { cbv = dm; cbr = r; }       // col partial, keep-first in r
    }
    mypart[c] =                                    // plain coalesced store
        ((unsigned long long)__float_as_uint(cbv) << 32) | (unsigned)(base_ib + cbr);
  }

  // row-argmin block reduction
  unsigned long long key[RPB];
#pragma unroll
  for (int r = 0; r < RPB; r++)
    key[r] = ((unsigned long long)__float_as_uint(bv[r]) << 32) | (unsigned)bi[r];
#pragma unroll
  for (int off = 32; off > 0; off >>= 1) {
#pragma unroll
    for (int r = 0; r < RPB; r++) {
      unsigned long long o = __shfl_down(key[r], off);
      if (o < key[r]) key[r] = o;
    }
  }
  if ((threadIdx.x & 63) == 0) {
    int w = threadIdx.x >> 6;
#pragma unroll
    for (int r = 0; r < RPB; r++) red[w][r] = key[r];
  }
  __syncthreads();
  if (threadIdx.x < RPB) {
    int r = threadIdx.x;
    unsigned long long k = red[0][r];
#pragma unroll
    for (int w = 1; w < 4; w++)
      if (red[w][r] < k) k = red[w][r];
    int idx = (int)(k & 0x7ffu);
    float e = __fsqrt_rn(__uint_as_float((unsigned)(k >> 32)));
    unsigned short pk = (unsigned short)idx;
    if (e > 3.0f) pk |= 0x8000u;                   // strict >, exact fp32
    gt0p[base + r] = pk;
    out_mind[base + r] = e;
  }
}

// 64 blocks x 256 threads: thread owns one column; min over the batch's 128
// block-partials. Reads coalesced (consecutive cols per lane).
__global__ __launch_bounds__(256) void sp_colreduce(
    const unsigned long long* __restrict__ part,
    unsigned long long* __restrict__ colkeys) {
  int b = blockIdx.x >> 3;
  int j = ((blockIdx.x & 7) << 8) + threadIdx.x;   // col in batch
  const unsigned long long* p = part + ((size_t)b * BPB) * SPN + j;
  unsigned long long k = ~0ull;
#pragma unroll 4
  for (int blk = 0; blk < BPB; blk++) {
    unsigned long long v = p[(size_t)blk * SPN];
    if (v < k) k = v;
  }
  colkeys[(b << 11) + j] = k;
}

__global__ __launch_bounds__(256) void SuperPointMatchesGenerator_56925496541369_final(
    const unsigned short* __restrict__ gt0p,
    const unsigned long long* __restrict__ colkeys, float* __restrict__ out) {
  int t = blockIdx.x * 256 + threadIdx.x;
  if (t >= SPT) return;
  int b = t >> 11, i = t & 2047, cb = b << 11;

  unsigned short p0 = gt0p[t];
  int m0 = p0 & 0x7ff;
  int back = (int)(colkeys[cb + m0] & 0x7ffu);
  bool ok0 = ((p0 & 0x8000u) == 0) && (back == i);
  out[t] = ok0 ? (float)m0 : -1.0f;

  int istar = (int)(colkeys[t] & 0x7ffu);          // gather form of the scatter
  unsigned short ps = gt0p[cb + istar];
  bool ok1 = (((int)(ps & 0x7ff)) == i) && ((ps & 0x8000u) == 0);
  out[SPT + t] = ok1 ? (float)istar : -1.0f;
}

// ---------- fallback (R5/R6-proven, 64KB ws) ----------
__global__ __launch_bounds__(256) void sp_fb_main(
    const float2* __restrict__ k0, const float2* __restrict__ k1,
    const float* __restrict__ T, unsigned short* __restrict__ gt0p,
    unsigned short* __restrict__ gt1, float* __restrict__ out_mind) {
  const bool mode1 = blockIdx.x >= SPN;
  const int base = (mode1 ? blockIdx.x - SPN : blockIdx.x) * 8;
  const int b = base >> 11, cb = b << 11;
  float rx[8], ry[8], rs[8], bv[8];
  int bi[8];
#pragma unroll
  for (int r = 0; r < 8; r++) { bv[r] = INFINITY; bi[r] = 0; }
  if (!mode1) {
#pragma unroll
    for (int r = 0; r < 8; r++) {
      float2 p = k0[base + r];
      sp_reproject(T, b, p.x, p.y, rx[r], ry[r], rs[r]);
    }
    for (int c = threadIdx.x; c < SPN; c += 256) {
      float2 p = k1[cb + c];
      float b2 = __fadd_rn(__fmul_rn(p.x, p.x), __fmul_rn(p.y, p.y));
#pragma unroll
      for (int r = 0; r < 8; r++) {
        float ab = __fadd_rn(__fmul_rn(rx[r], p.x), __fmul_rn(ry[r], p.y));
        float d2 = __fsub_rn(__fadd_rn(rs[r], b2), __fmul_rn(2.0f, ab));
        float dm = fmaxf(d2, 0.0f);
        if (dm < bv[r]) { bv[r] = dm; bi[r] = c; }
      }
    }
  } else {
#pragma unroll
    for (int r = 0; r < 8; r++) {
      float2 p = k1[base + r];
      rx[r] = p.x; ry[r] = p.y;
      rs[r] = __fadd_rn(__fmul_rn(p.x, p.x), __fmul_rn(p.y, p.y));
    }
    for (int c = threadIdx.x; c < SPN; c += 256) {
      float2 p = k0[cb + c];
      float cx, cy, a2;
      sp_reproject(T, b, p.x, p.y, cx, cy, a2);
#pragma unroll
      for (int r = 0; r < 8; r++) {
        float ab = __fadd_rn(__fmul_rn(rx[r], cx), __fmul_rn(ry[r], cy));
        float d2 = __fsub_rn(__fadd_rn(a2, rs[r]), __fmul_rn(2.0f, ab));
        float dm = fmaxf(d2, 0.0f);
        if (dm < bv[r]) { bv[r] = dm; bi[r] = c; }
      }
    }
  }
  unsigned long long key[8];
#pragma unroll
  for (int r = 0; r < 8; r++)
    key[r] = ((unsigned long long)__float_as_uint(bv[r]) << 32) | (unsigned)bi[r];
#pragma unroll
  for (int off = 32; off > 0; off >>= 1) {
#pragma unroll
    for (int r = 0; r < 8; r++) {
      unsigned long long o = __shfl_down(key[r], off);
      if (o < key[r]) key[r] = o;
    }
  }
  __shared__ unsigned long long part[4][8];
  if ((threadIdx.x & 63) == 0) {
    int w = threadIdx.x >> 6;
#pragma unroll
    for (int r = 0; r < 8; r++) part[w][r] = key[r];
  }
  __syncthreads();
  if (threadIdx.x < 8) {
    int r = threadIdx.x;
    unsigned long long k = part[0][r];
#pragma unroll
    for (int w = 1; w < 4; w++)
      if (part[w][r] < k) k = part[w][r];
    int idx = (int)(k & 0x7ffu);
    if (!mode1) {
      float e = __fsqrt_rn(__uint_as_float((unsigned)(k >> 32)));
      unsigned short pk = (unsigned short)idx;
      if (e > 3.0f) pk |= 0x8000u;
      gt0p[base + r] = pk;
      out_mind[base + r] = e;
    } else {
      gt1[base + r] = (unsigned short)idx;
    }
  }
}

__global__ __launch_bounds__(256) void sp_fb_final(
    const unsigned short* __restrict__ gt0p, const unsigned short* __restrict__ gt1,
    float* __restrict__ out) {
  int t = blockIdx.x * 256 + threadIdx.x;
  if (t >= SPT) return;
  int b = t >> 11, i = t & 2047, cb = b << 11;
  unsigned short p0 = gt0p[t];
  int m0 = p0 & 0x7ff;
  bool ok0 = ((p0 & 0x8000u) == 0) && ((int)gt1[cb + m0] == i);
  out[t] = ok0 ? (float)m0 : -1.0f;
  int istar = gt1[t];
  unsigned short ps = gt0p[cb + istar];
  bool ok1 = (((int)(ps & 0x7ff)) == i) && ((ps & 0x8000u) == 0);
  out[SPT + t] = ok1 ? (float)istar : -1.0f;
}

extern "C" void kernel_launch(void* const* d_in, const int* in_sizes, int n_in,
                              void* d_out, int out_size, void* d_ws, size_t ws_size,
                              hipStream_t stream) {
  (void)in_sizes; (void)n_in; (void)out_size;
  const float2* k0 = (const float2*)d_in[0];
  const float2* k1 = (const float2*)d_in[1];
  const float* T   = (const float*)d_in[2];
  float* out = (float*)d_out;

  const size_t npart = (size_t)(SPT / RPB) * BPB == 0 ? 0 : (size_t)1024 * SPN; // 2.1M
  const size_t need = npart * 8 + (size_t)SPT * 8 + (size_t)SPT * 2;            // ~16.2MB
  if (ws_size >= need) {
    unsigned long long* part = (unsigned long long*)d_ws;        // 16 MB
    unsigned long long* colkeys = part + npart;                  // 128 KB
    unsigned short* gt0p = (unsigned short*)(colkeys + SPT);     // 32 KB
    SuperPointMatchesGenerator_56925496541369_kernel<<<SPT / RPB, 256, 0, stream>>>(
        k0, k1, T, gt0p, part, out + 2 * SPT);
    sp_colreduce<<<SPT / 256, 256, 0, stream>>>(part, colkeys);
    SuperPointMatchesGenerator_56925496541369_final<<<SPT / 256, 256, 0, stream>>>(
        gt0p, colkeys, out);
  } else {
    unsigned short* gt0p = (unsigned short*)d_ws;
    unsigned short* gt1  = gt0p + SPT;
    sp_fb_main<<<2 * SPN, 256, 0, stream>>>(k0, k1, T, gt0p, gt1, out + 2 * SPT);
    sp_fb_final<<<SPT / 256, 256, 0, stream>>>(gt0p, gt1, out);
  }
}

// Round 9
// 82.624 us; speedup vs baseline: 1.1631x; 1.1631x over previous
//
#include <hip/hip_runtime.h>

// SuperPointMatchesGenerator: B=8, N0=N1=2048 mutual-NN under homography.
// d_out f32, concat: gt_matches0[8,2048] | gt_matches1[8,2048] | min_dist0[8,2048]
//
// R9 = R6 structure (best measured: 84.1us; R7/R8 dedup variants regressed:
// 90.0/96.1 - extra dispatch + partial traffic + col-select chain cost more
// than recomputing d2 twice) + issue-efficiency fixes on main:
//  - __launch_bounds__(256, 4): R6 main compiled to 48 VGPRs (8-waves/SIMD
//    target) leaving no registers for load pipelining -> per-c-iter waitcnt
//    stall. 128-VGPR cap keeps 16 waves/CU (plenty for L1/L2-resident data)
//    and lets the scheduler hoist loads.
//  - manual 2x c-unroll with BOTH float4 loads issued before the 2x72-op
//    compute body (explicit memory-level parallelism). Keep-first preserved:
//    c is processed before c+256, ascending; strict <.
//
// FP exactness vs numpy-f32 (no FMA contraction, explicit __f*_rn):
//   p_i = (H[i0]*x + H[i1]*y) + H[i2];  X = p0/(p2+1e-8);  a2 = X*X + Y*Y;
//   d2  = (a2 + b2) - 2*ab;  compare max(d2,0); winner e = sqrt(max(d2,0)).
// Keep-first argmin at every level (strict <, ascending index, u64
// (d2bits<<32|idx) min reduction).
//
// ws (full path, 576KB): q0 f4[16K] | q1 f4[16K] | gt0p u16[16K] | gt1 u16[16K]
// Fallback (ws < needed): R5-proven 64KB brute force.

#define SPN 2048
#define SPT 16384

__device__ __forceinline__ void sp_reproject(const float* __restrict__ T, int b,
                                             float x, float y,
                                             float& X, float& Y, float& S) {
  const float* H = T + b * 9;
  float p0 = __fadd_rn(__fadd_rn(__fmul_rn(H[0], x), __fmul_rn(H[1], y)), H[2]);
  float p1 = __fadd_rn(__fadd_rn(__fmul_rn(H[3], x), __fmul_rn(H[4], y)), H[5]);
  float p2 = __fadd_rn(__fadd_rn(__fmul_rn(H[6], x), __fmul_rn(H[7], y)), H[8]);
  float den = __fadd_rn(p2, 1e-8f);
  X = __fdiv_rn(p0, den);
  Y = __fdiv_rn(p1, den);
  S = __fadd_rn(__fmul_rn(X, X), __fmul_rn(Y, Y));
}

__global__ __launch_bounds__(256) void sp_prep(
    const float2* __restrict__ k0, const float2* __restrict__ k1,
    const float* __restrict__ T, float4* __restrict__ q0, float4* __restrict__ q1) {
  int t = blockIdx.x * 256 + threadIdx.x;
  if (t < SPT) {
    float2 p = k0[t];
    float X, Y, S;
    sp_reproject(T, t >> 11, p.x, p.y, X, Y, S);
    q0[t] = make_float4(X, Y, S, 0.0f);
  } else {
    int u = t - SPT;
    float2 p = k1[u];
    float S = __fadd_rn(__fmul_rn(p.x, p.x), __fmul_rn(p.y, p.y));
    q1[u] = make_float4(p.x, p.y, S, 0.0f);
  }
}

__device__ __forceinline__ void sp_row8(
    const float rx[8], const float ry[8], const float rs[8],
    float bv[8], int bi[8], float4 v, int c) {
#pragma unroll
  for (int r = 0; r < 8; r++) {
    float ab = __fadd_rn(__fmul_rn(rx[r], v.x), __fmul_rn(ry[r], v.y));
    float d2 = __fsub_rn(__fadd_rn(rs[r], v.z), __fmul_rn(2.0f, ab));
    float dm = fmaxf(d2, 0.0f);
    if (dm < bv[r]) { bv[r] = dm; bi[r] = c; }
  }
}

__global__ __launch_bounds__(256, 4) void SuperPointMatchesGenerator_56925496541369_kernel(
    const float4* __restrict__ q0, const float4* __restrict__ q1,
    unsigned short* __restrict__ gt0p, unsigned short* __restrict__ gt1,
    float* __restrict__ out_mind) {
  const bool m1 = blockIdx.x >= SPN;              // block-uniform
  const int base = (m1 ? blockIdx.x - SPN : blockIdx.x) * 8;
  const int b = base >> 11, cb = b << 11;
  const float4* __restrict__ qr = m1 ? q1 : q0;   // rows
  const float4* __restrict__ qc = (m1 ? q0 : q1) + cb;  // candidates

  float rx[8], ry[8], rs[8], bv[8];
  int bi[8];
#pragma unroll
  for (int r = 0; r < 8; r++) {
    float4 v = qr[base + r];                      // uniform addr -> broadcast
    rx[r] = v.x; ry[r] = v.y; rs[r] = v.z;
    bv[r] = INFINITY; bi[r] = 0;
  }

  // 2048 candidates, 2x unrolled with both loads hoisted (explicit MLP).
#pragma unroll 1
  for (int c = threadIdx.x; c < SPN; c += 512) {
    float4 va = qc[c];
    float4 vb = qc[c + 256];
    sp_row8(rx, ry, rs, bv, bi, va, c);           // ascending: c first
    sp_row8(rx, ry, rs, bv, bi, vb, c + 256);
  }

  unsigned long long key[8];
#pragma unroll
  for (int r = 0; r < 8; r++)
    key[r] = ((unsigned long long)__float_as_uint(bv[r]) << 32) | (unsigned)bi[r];
#pragma unroll
  for (int off = 32; off > 0; off >>= 1) {
#pragma unroll
    for (int r = 0; r < 8; r++) {
      unsigned long long o = __shfl_down(key[r], off);
      if (o < key[r]) key[r] = o;
    }
  }
  __shared__ unsigned long long part[4][8];
  if ((threadIdx.x & 63) == 0) {
    int w = threadIdx.x >> 6;
#pragma unroll
    for (int r = 0; r < 8; r++) part[w][r] = key[r];
  }
  __syncthreads();                                 // single barrier
  if (threadIdx.x < 8) {
    int r = threadIdx.x;
    unsigned long long k = part[0][r];
#pragma unroll
    for (int w = 1; w < 4; w++)
      if (part[w][r] < k) k = part[w][r];
    int idx = (int)(k & 0x7ffu);
    if (!m1) {
      float e = __fsqrt_rn(__uint_as_float((unsigned)(k >> 32)));
      unsigned short pk = (unsigned short)idx;
      if (e > 3.0f) pk |= 0x8000u;                 // strict >, exact fp32
      gt0p[base + r] = pk;
      out_mind[base + r] = e;
    } else {
      gt1[base + r] = (unsigned short)idx;
    }
  }
}

__global__ __launch_bounds__(256) void SuperPointMatchesGenerator_56925496541369_final(
    const unsigned short* __restrict__ gt0p, const unsigned short* __restrict__ gt1,
    float* __restrict__ out) {
  int t = blockIdx.x * 256 + threadIdx.x;
  if (t >= SPT) return;
  int b = t >> 11, i = t & 2047, cb = b << 11;

  unsigned short p0 = gt0p[t];
  int m0 = p0 & 0x7ff;
  bool ok0 = ((p0 & 0x8000u) == 0) && ((int)gt1[cb + m0] == i);
  out[t] = ok0 ? (float)m0 : -1.0f;

  int istar = gt1[t];                              // gather form of the scatter
  unsigned short ps = gt0p[cb + istar];
  bool ok1 = (((int)(ps & 0x7ff)) == i) && ((ps & 0x8000u) == 0);
  out[SPT + t] = ok1 ? (float)istar : -1.0f;
}

// ---------- fallback (R5-proven, 64KB ws) ----------
__global__ __launch_bounds__(256) void sp_fb_main(
    const float2* __restrict__ k0, const float2* __restrict__ k1,
    const float* __restrict__ T, unsigned short* __restrict__ gt0p,
    unsigned short* __restrict__ gt1, float* __restrict__ out_mind) {
  const bool mode1 = blockIdx.x >= SPN;
  const int base = (mode1 ? blockIdx.x - SPN : blockIdx.x) * 8;
  const int b = base >> 11, cb = b << 11;
  float rx[8], ry[8], rs[8], bv[8];
  int bi[8];
#pragma unroll
  for (int r = 0; r < 8; r++) { bv[r] = INFINITY; bi[r] = 0; }
  if (!mode1) {
#pragma unroll
    for (int r = 0; r < 8; r++) {
      float2 p = k0[base + r];
      sp_reproject(T, b, p.x, p.y, rx[r], ry[r], rs[r]);
    }
    for (int c = threadIdx.x; c < SPN; c += 256) {
      float2 p = k1[cb + c];
      float b2 = __fadd_rn(__fmul_rn(p.x, p.x), __fmul_rn(p.y, p.y));
#pragma unroll
      for (int r = 0; r < 8; r++) {
        float ab = __fadd_rn(__fmul_rn(rx[r], p.x), __fmul_rn(ry[r], p.y));
        float d2 = __fsub_rn(__fadd_rn(rs[r], b2), __fmul_rn(2.0f, ab));
        float dm = fmaxf(d2, 0.0f);
        if (dm < bv[r]) { bv[r] = dm; bi[r] = c; }
      }
    }
  } else {
#pragma unroll
    for (int r = 0; r < 8; r++) {
      float2 p = k1[base + r];
      rx[r] = p.x; ry[r] = p.y;
      rs[r] = __fadd_rn(__fmul_rn(p.x, p.x), __fmul_rn(p.y, p.y));
    }
    for (int c = threadIdx.x; c < SPN; c += 256) {
      float2 p = k0[cb + c];
      float cx, cy, a2;
      sp_reproject(T, b, p.x, p.y, cx, cy, a2);
#pragma unroll
      for (int r = 0; r < 8; r++) {
        float ab = __fadd_rn(__fmul_rn(rx[r], cx), __fmul_rn(ry[r], cy));
        float d2 = __fsub_rn(__fadd_rn(a2, rs[r]), __fmul_rn(2.0f, ab));
        float dm = fmaxf(d2, 0.0f);
        if (dm < bv[r]) { bv[r] = dm; bi[r] = c; }
      }
    }
  }
  unsigned long long key[8];
#pragma unroll
  for (int r = 0; r < 8; r++)
    key[r] = ((unsigned long long)__float_as_uint(bv[r]) << 32) | (unsigned)bi[r];
#pragma unroll
  for (int off = 32; off > 0; off >>= 1) {
#pragma unroll
    for (int r = 0; r < 8; r++) {
      unsigned long long o = __shfl_down(key[r], off);
      if (o < key[r]) key[r] = o;
    }
  }
  __shared__ unsigned long long part[4][8];
  if ((threadIdx.x & 63) == 0) {
    int w = threadIdx.x >> 6;
#pragma unroll
    for (int r = 0; r < 8; r++) part[w][r] = key[r];
  }
  __syncthreads();
  if (threadIdx.x < 8) {
    int r = threadIdx.x;
    unsigned long long k = part[0][r];
#pragma unroll
    for (int w = 1; w < 4; w++)
      if (part[w][r] < k) k = part[w][r];
    int idx = (int)(k & 0x7ffu);
    if (!mode1) {
      float e = __fsqrt_rn(__uint_as_float((unsigned)(k >> 32)));
      unsigned short pk = (unsigned short)idx;
      if (e > 3.0f) pk |= 0x8000u;
      gt0p[base + r] = pk;
      out_mind[base + r] = e;
    } else {
      gt1[base + r] = (unsigned short)idx;
    }
  }
}

extern "C" void kernel_launch(void* const* d_in, const int* in_sizes, int n_in,
                              void* d_out, int out_size, void* d_ws, size_t ws_size,
                              hipStream_t stream) {
  (void)in_sizes; (void)n_in; (void)out_size;
  const float2* k0 = (const float2*)d_in[0];
  const float2* k1 = (const float2*)d_in[1];
  const float* T   = (const float*)d_in[2];
  float* out = (float*)d_out;

  const size_t need = (size_t)2 * SPT * sizeof(float4) + (size_t)2 * SPT * sizeof(unsigned short);
  if (ws_size >= need) {
    float4* q0 = (float4*)d_ws;                          // 256 KB
    float4* q1 = q0 + SPT;                               // 256 KB
    unsigned short* gt0p = (unsigned short*)(q1 + SPT);  // 32 KB
    unsigned short* gt1  = gt0p + SPT;                   // 32 KB
    sp_prep<<<2 * SPT / 256, 256, 0, stream>>>(k0, k1, T, q0, q1);
    SuperPointMatchesGenerator_56925496541369_kernel<<<2 * SPN, 256, 0, stream>>>(
        q0, q1, gt0p, gt1, out + 2 * SPT);
    SuperPointMatchesGenerator_56925496541369_final<<<SPT / 256, 256, 0, stream>>>(
        gt0p, gt1, out);
  } else {
    unsigned short* gt0p = (unsigned short*)d_ws;
    unsigned short* gt1  = gt0p + SPT;
    sp_fb_main<<<2 * SPN, 256, 0, stream>>>(k0, k1, T, gt0p, gt1, out + 2 * SPT);
    SuperPointMatchesGenerator_56925496541369_final<<<SPT / 256, 256, 0, stream>>>(
        gt0p, gt1, out);
  }
}